// Round 6
// baseline (273.540 us; speedup 1.0000x reference)
//
#include <hip/hip_runtime.h>
#include <hip/hip_cooperative_groups.h>
#include <math.h>

// Problem geometry (fixed by reference):
//   x: [B=16, C=256, 128, 128] fp32 ; H = 16 ; spatial N = 16384
#define BATCH 16
#define CH    256
#define HID   16
#define SPAT  16384            // 128*128
#define NPLANE (BATCH * CH)    // 4096 planes, 64 KiB fp32 each

typedef float vfloat4 __attribute__((ext_vector_type(4)));

// Per-wave plane processing: 64 lanes x 64 float4-iters = 16384 elems.
// Retention split of the 64 iters:
#define ITER_REG   28                       // 56 packed-bf16 VGPRs / thread
#define ITER_LDS   19                       // 19*2048 uint32 = 155,648 B LDS
#define ITER_HOLD  (ITER_REG + ITER_LDS)    // 47 ; iters 47..63 re-read (71 MB)
#define ITER_TOTAL 64

namespace cg = cooperative_groups;

// bf16 round-to-nearest-even, plain integer ops (finite inputs only)
__device__ __forceinline__ unsigned short f2bf(float f) {
    unsigned int u = __builtin_bit_cast(unsigned int, f);
    u += 0x7fffu + ((u >> 16) & 1u);
    return (unsigned short)(u >> 16);
}
__device__ __forceinline__ float bf2f(unsigned short h) {
    unsigned int u = ((unsigned int)h) << 16;
    return __builtin_bit_cast(float, u);
}
__device__ __forceinline__ unsigned pack_bf2(float a, float b) {
    return (unsigned)f2bf(a) | ((unsigned)f2bf(b) << 16);
}
__device__ __forceinline__ vfloat4 unpack2(unsigned u0, unsigned u1, float m) {
    vfloat4 v;
    v.x = bf2f((unsigned short)(u0 & 0xffffu)) * m;
    v.y = bf2f((unsigned short)(u0 >> 16))     * m;
    v.z = bf2f((unsigned short)(u1 & 0xffffu)) * m;
    v.w = bf2f((unsigned short)(u1 >> 16))     * m;
    return v;
}

// ---------------------------------------------------------------------------
// Cooperative persistent kernel: 256 blocks x 1024 threads, 1 block/CU.
// Phase 1: stats per plane (wave-per-plane) + retain bf16(x) in regs+LDS.
// grid.sync()
// Phase 2: each block computes the SE chain for its batch row (redundant x16).
// Phase 3: out = x~ * mask, NT stores; non-retained tail re-read (L3-hot).
// ---------------------------------------------------------------------------
__global__ __launch_bounds__(1024, 4) void coop_kernel(
    const float* __restrict__ x,
    const float* __restrict__ sw1, const float* __restrict__ sb1,
    const float* __restrict__ sw2, const float* __restrict__ sb2,
    const float* __restrict__ mw1, const float* __restrict__ mb1,
    const float* __restrict__ mw2, const float* __restrict__ mb2,
    const float* __restrict__ bw,  const float* __restrict__ bb,
    const float* __restrict__ fw1, const float* __restrict__ fb1,
    const float* __restrict__ fw2, const float* __restrict__ fb2,
    float* __restrict__ out,
    float* __restrict__ mean_g, float* __restrict__ std_g)
{
    __shared__ unsigned lds_data[ITER_LDS * 2048];  // 155,648 B retained bf16
    __shared__ float s_desc[2 * CH];                // SE scratch (5,248 B total)
    __shared__ float s_h[HID];
    __shared__ float s_fused[2 * CH];
    __shared__ float s_g[CH];
    __shared__ float s_mask[16];

    const int tid  = threadIdx.x;
    const int w    = tid >> 6;        // wave 0..15  -> plane within block
    const int lane = tid & 63;
    const int plane = blockIdx.x * 16 + w;   // global (b,c) plane

    const vfloat4* p4 = reinterpret_cast<const vfloat4*>(x + (long long)plane * SPAT);

    // ---------------- Phase 1: stats + retention ----------------
    float s = 0.f, s2 = 0.f;
    unsigned r[2 * ITER_REG];

    #pragma unroll
    for (int i = 0; i < ITER_REG; ++i) {
        vfloat4 v = __builtin_nontemporal_load(&p4[lane + i * 64]);
        s  += (v.x + v.y) + (v.z + v.w);
        s2  = fmaf(v.x, v.x, fmaf(v.y, v.y, fmaf(v.z, v.z, fmaf(v.w, v.w, s2))));
        r[2 * i]     = pack_bf2(v.x, v.y);
        r[2 * i + 1] = pack_bf2(v.z, v.w);
    }
    #pragma unroll
    for (int i = 0; i < ITER_LDS; ++i) {
        vfloat4 v = __builtin_nontemporal_load(&p4[lane + (ITER_REG + i) * 64]);
        s  += (v.x + v.y) + (v.z + v.w);
        s2  = fmaf(v.x, v.x, fmaf(v.y, v.y, fmaf(v.z, v.z, fmaf(v.w, v.w, s2))));
        uint2 u; u.x = pack_bf2(v.x, v.y); u.y = pack_bf2(v.z, v.w);
        *reinterpret_cast<uint2*>(&lds_data[i * 2048 + tid * 2]) = u;
    }
    // Tail read with CACHED loads, last in phase 1 -> most recent in L3.
    #pragma unroll
    for (int i = ITER_HOLD; i < ITER_TOTAL; ++i) {
        vfloat4 v = p4[lane + i * 64];
        s  += (v.x + v.y) + (v.z + v.w);
        s2  = fmaf(v.x, v.x, fmaf(v.y, v.y, fmaf(v.z, v.z, fmaf(v.w, v.w, s2))));
    }

    // wave64 butterfly reduce; lane 0 publishes plane stats
    #pragma unroll
    for (int off = 32; off > 0; off >>= 1) {
        s  += __shfl_xor(s,  off);
        s2 += __shfl_xor(s2, off);
    }
    if (lane == 0) {
        const float m   = s * (1.f / SPAT);
        const float var = s2 * (1.f / SPAT) - m * m;
        mean_g[plane] = m;
        std_g[plane]  = sqrtf(fmaxf(var, 0.f));
    }

    cg::this_grid().sync();

    // ---------------- Phase 2: SE chain for this block's batch row ----------
    const int brow = blockIdx.x >> 4;     // 16 blocks share a batch row
    if (tid < CH) {
        s_desc[tid]      = std_g [brow * CH + tid];
        s_desc[CH + tid] = mean_g[brow * CH + tid];
    }
    __syncthreads();

    auto se_l1 = [&](const float* desc, const float* __restrict__ w1,
                     const float* __restrict__ b1) {
        if (tid < 256) {
            const int hh = tid >> 4;
            const int j  = tid & 15;
            float acc = 0.f;
            #pragma unroll
            for (int k = 0; k < 16; ++k) {
                const int c = j * 16 + k;
                acc += desc[c] * w1[hh * CH + c];
            }
            #pragma unroll
            for (int off = 1; off < 16; off <<= 1)
                acc += __shfl_xor(acc, off, 16);
            if (j == 0) s_h[hh] = fmaxf(acc + b1[hh], 0.f);
        }
    };
    auto se_l2 = [&](const float* __restrict__ w2, const float* __restrict__ b2,
                     float* outbuf) {
        if (tid < 256) {
            float acc = b2[tid];
            const vfloat4* w4 = reinterpret_cast<const vfloat4*>(w2 + tid * HID);
            #pragma unroll
            for (int q = 0; q < 4; ++q) {
                const vfloat4 wv = w4[q];
                acc += s_h[q * 4 + 0] * wv.x + s_h[q * 4 + 1] * wv.y
                     + s_h[q * 4 + 2] * wv.z + s_h[q * 4 + 3] * wv.w;
            }
            outbuf[tid] = acc;
        }
    };

    se_l1(s_desc, sw1, sb1);
    __syncthreads();
    se_l2(sw2, sb2, s_fused);
    __syncthreads();
    se_l1(s_desc + CH, mw1, mb1);
    __syncthreads();
    se_l2(mw2, mb2, s_fused + CH);
    __syncthreads();

    if (tid < 256) {   // bottleneck: g[c] = relu(fused . bw[c,:] + bb[c])
        float acc = bb[tid];
        const vfloat4* wrow = reinterpret_cast<const vfloat4*>(bw + tid * (2 * CH));
        const vfloat4* f4   = reinterpret_cast<const vfloat4*>(s_fused);
        #pragma unroll 8
        for (int q = 0; q < (2 * CH) / 4; ++q) {
            const vfloat4 wv = wrow[q];
            const vfloat4 fv = f4[q];
            acc += fv.x * wv.x + fv.y * wv.y + fv.z * wv.z + fv.w * wv.w;
        }
        s_g[tid] = fmaxf(acc, 0.f);
    }
    __syncthreads();

    se_l1(s_g, fw1, fb1);
    __syncthreads();
    if (tid < 256) {
        float acc = fb2[tid];
        const vfloat4* w4 = reinterpret_cast<const vfloat4*>(fw2 + tid * HID);
        #pragma unroll
        for (int q = 0; q < 4; ++q) {
            const vfloat4 wv = w4[q];
            acc += s_h[q * 4 + 0] * wv.x + s_h[q * 4 + 1] * wv.y
                 + s_h[q * 4 + 2] * wv.z + s_h[q * 4 + 3] * wv.w;
        }
        const float sig = 1.f / (1.f + expf(-acc));
        if ((tid >> 4) == (blockIdx.x & 15))   // this block's 16 channels
            s_mask[tid & 15] = sig;
    }
    __syncthreads();

    // ---------------- Phase 3: scale & store ----------------
    const float m = s_mask[w];
    vfloat4* o4 = reinterpret_cast<vfloat4*>(out + (long long)plane * SPAT);

    // 1) non-retained tail FIRST (exact fp32, likely L3-hot from phase 1)
    #pragma unroll
    for (int i = ITER_HOLD; i < ITER_TOTAL; ++i) {
        vfloat4 v = p4[lane + i * 64];
        v *= m;
        __builtin_nontemporal_store(v, &o4[lane + i * 64]);
    }
    // 2) register-retained bf16
    #pragma unroll
    for (int i = 0; i < ITER_REG; ++i) {
        vfloat4 v = unpack2(r[2 * i], r[2 * i + 1], m);
        __builtin_nontemporal_store(v, &o4[lane + i * 64]);
    }
    // 3) LDS-retained bf16
    #pragma unroll
    for (int i = 0; i < ITER_LDS; ++i) {
        const uint2 u = *reinterpret_cast<const uint2*>(&lds_data[i * 2048 + tid * 2]);
        vfloat4 v = unpack2(u.x, u.y, m);
        __builtin_nontemporal_store(v, &o4[lane + (ITER_REG + i) * 64]);
    }
}

// ===========================================================================
// Fallback path (R3): 3 plain kernels, used only if cooperative launch fails.
// ===========================================================================
__global__ __launch_bounds__(256) void stats_kernel(const float* __restrict__ x,
                                                    float* __restrict__ mean_g,
                                                    float* __restrict__ std_g)
{
    const long long base = (long long)blockIdx.x * SPAT;
    const vfloat4* x4 = reinterpret_cast<const vfloat4*>(x + base);
    float s = 0.f, s2 = 0.f;
    #pragma unroll
    for (int i = 0; i < 16; ++i) {
        vfloat4 v = x4[threadIdx.x + i * 256];
        s  += v.x + v.y + v.z + v.w;
        s2 += v.x * v.x + v.y * v.y + v.z * v.z + v.w * v.w;
    }
    #pragma unroll
    for (int off = 32; off > 0; off >>= 1) {
        s  += __shfl_xor(s,  off);
        s2 += __shfl_xor(s2, off);
    }
    __shared__ float ws[4], ws2[4];
    const int wave = threadIdx.x >> 6;
    const int lane = threadIdx.x & 63;
    if (lane == 0) { ws[wave] = s; ws2[wave] = s2; }
    __syncthreads();
    if (threadIdx.x == 0) {
        const float ts  = ws[0]  + ws[1]  + ws[2]  + ws[3];
        const float ts2 = ws2[0] + ws2[1] + ws2[2] + ws2[3];
        const float m   = ts * (1.f / SPAT);
        const float var = ts2 * (1.f / SPAT) - m * m;
        mean_g[blockIdx.x] = m;
        std_g[blockIdx.x]  = sqrtf(fmaxf(var, 0.f));
    }
}

__global__ __launch_bounds__(256) void se_chain_kernel(
    const float* __restrict__ mean_g, const float* __restrict__ std_g,
    const float* __restrict__ sw1, const float* __restrict__ sb1,
    const float* __restrict__ sw2, const float* __restrict__ sb2,
    const float* __restrict__ mw1, const float* __restrict__ mb1,
    const float* __restrict__ mw2, const float* __restrict__ mb2,
    const float* __restrict__ bw,  const float* __restrict__ bb,
    const float* __restrict__ fw1, const float* __restrict__ fb1,
    const float* __restrict__ fw2, const float* __restrict__ fb2,
    float* __restrict__ mask_g)
{
    const int b   = blockIdx.x;
    const int tid = threadIdx.x;

    __shared__ float s_desc[2 * CH];
    __shared__ float s_h[HID];
    __shared__ float s_fused[2 * CH];
    __shared__ float s_g[CH];

    s_desc[tid]      = std_g [b * CH + tid];
    s_desc[CH + tid] = mean_g[b * CH + tid];
    __syncthreads();

    auto se_l1 = [&](const float* desc, const float* __restrict__ w1,
                     const float* __restrict__ b1) {
        const int hh = tid >> 4;
        const int j  = tid & 15;
        float acc = 0.f;
        #pragma unroll
        for (int k = 0; k < 16; ++k) {
            const int c = j * 16 + k;
            acc += desc[c] * w1[hh * CH + c];
        }
        #pragma unroll
        for (int off = 1; off < 16; off <<= 1)
            acc += __shfl_xor(acc, off, 16);
        if (j == 0) s_h[hh] = fmaxf(acc + b1[hh], 0.f);
    };
    auto se_l2 = [&](const float* __restrict__ w2, const float* __restrict__ b2,
                     float* outbuf) {
        float acc = b2[tid];
        const vfloat4* w4 = reinterpret_cast<const vfloat4*>(w2 + tid * HID);
        #pragma unroll
        for (int q = 0; q < 4; ++q) {
            const vfloat4 wv = w4[q];
            acc += s_h[q * 4 + 0] * wv.x + s_h[q * 4 + 1] * wv.y
                 + s_h[q * 4 + 2] * wv.z + s_h[q * 4 + 3] * wv.w;
        }
        outbuf[tid] = acc;
    };

    se_l1(s_desc, sw1, sb1);
    __syncthreads();
    se_l2(sw2, sb2, s_fused);
    __syncthreads();
    se_l1(s_desc + CH, mw1, mb1);
    __syncthreads();
    se_l2(mw2, mb2, s_fused + CH);
    __syncthreads();
    {
        float acc = bb[tid];
        const vfloat4* wrow = reinterpret_cast<const vfloat4*>(bw + tid * (2 * CH));
        const vfloat4* f4   = reinterpret_cast<const vfloat4*>(s_fused);
        #pragma unroll 8
        for (int q = 0; q < (2 * CH) / 4; ++q) {
            const vfloat4 wv = wrow[q];
            const vfloat4 fv = f4[q];
            acc += fv.x * wv.x + fv.y * wv.y + fv.z * wv.z + fv.w * wv.w;
        }
        s_g[tid] = fmaxf(acc, 0.f);
    }
    __syncthreads();
    se_l1(s_g, fw1, fb1);
    __syncthreads();
    {
        float acc = fb2[tid];
        const vfloat4* w4 = reinterpret_cast<const vfloat4*>(fw2 + tid * HID);
        #pragma unroll
        for (int q = 0; q < 4; ++q) {
            const vfloat4 wv = w4[q];
            acc += s_h[q * 4 + 0] * wv.x + s_h[q * 4 + 1] * wv.y
                 + s_h[q * 4 + 2] * wv.z + s_h[q * 4 + 3] * wv.w;
        }
        mask_g[b * CH + tid] = 1.f / (1.f + expf(-acc));
    }
}

__global__ __launch_bounds__(256) void scale_kernel(const float* __restrict__ x,
                                                    const float* __restrict__ mask,
                                                    float* __restrict__ out)
{
    const int plane = (NPLANE - 1) - blockIdx.x;
    const float m = mask[plane];
    const long long base = (long long)plane * SPAT;
    const vfloat4* x4 = reinterpret_cast<const vfloat4*>(x + base);
    vfloat4*       o4 = reinterpret_cast<vfloat4*>(out + base);
    #pragma unroll
    for (int i = 0; i < 16; ++i) {
        vfloat4 v = x4[threadIdx.x + i * 256];
        v *= m;
        __builtin_nontemporal_store(v, &o4[threadIdx.x + i * 256]);
    }
}

// ---------------------------------------------------------------------------
extern "C" void kernel_launch(void* const* d_in, const int* in_sizes, int n_in,
                              void* d_out, int out_size, void* d_ws, size_t ws_size,
                              hipStream_t stream)
{
    const float* x   = (const float*)d_in[0];
    const float* sw1 = (const float*)d_in[1];
    const float* sb1 = (const float*)d_in[2];
    const float* sw2 = (const float*)d_in[3];
    const float* sb2 = (const float*)d_in[4];
    const float* mw1 = (const float*)d_in[5];
    const float* mb1 = (const float*)d_in[6];
    const float* mw2 = (const float*)d_in[7];
    const float* mb2 = (const float*)d_in[8];
    const float* bw  = (const float*)d_in[9];
    const float* bb  = (const float*)d_in[10];
    const float* fw1 = (const float*)d_in[11];
    const float* fb1 = (const float*)d_in[12];
    const float* fw2 = (const float*)d_in[13];
    const float* fb2 = (const float*)d_in[14];

    float* out = (float*)d_out;

    float* mean_g = (float*)d_ws;
    float* std_g  = mean_g + NPLANE;
    float* mask_g = std_g  + NPLANE;   // fallback path only

    void* args[] = {
        (void*)&x,
        (void*)&sw1, (void*)&sb1, (void*)&sw2, (void*)&sb2,
        (void*)&mw1, (void*)&mb1, (void*)&mw2, (void*)&mb2,
        (void*)&bw,  (void*)&bb,
        (void*)&fw1, (void*)&fb1, (void*)&fw2, (void*)&fb2,
        (void*)&out, (void*)&mean_g, (void*)&std_g
    };

    hipError_t err = hipLaunchCooperativeKernel(
        (const void*)coop_kernel, dim3(256), dim3(1024), args, 0, stream);

    if (err != hipSuccess) {
        // Fallback: R3 three-kernel path.
        stats_kernel<<<NPLANE, 256, 0, stream>>>(x, mean_g, std_g);
        se_chain_kernel<<<BATCH, 256, 0, stream>>>(mean_g, std_g,
                                                   sw1, sb1, sw2, sb2,
                                                   mw1, mb1, mw2, mb2,
                                                   bw, bb,
                                                   fw1, fb1, fw2, fb2,
                                                   mask_g);
        scale_kernel<<<NPLANE, 256, 0, stream>>>(x, mask_g, out);
    }
}